// Round 1
// baseline (2884.888 us; speedup 1.0000x reference)
//
#include <hip/hip_runtime.h>

// DCRNN: 2x (scatter-add SpMM -> GRU cell). N=50000 nodes, E=800000 edges, D=64.
#define NN 50000
#define NE 800000
#define DD 64
#define NT (NN / 16)   // 3125 node-tiles of 16

typedef float     f32x4 __attribute__((ext_vector_type(4)));
typedef _Float16  f16x8 __attribute__((ext_vector_type(8)));
typedef _Float16  f16x4 __attribute__((ext_vector_type(4)));

// ---------------------------------------------------------------------------
// Convert x [N,64] f32 -> fp16, and the 4 weight matrices [192][64] -> fp16.
// ---------------------------------------------------------------------------
__global__ void convert_kernel(const float* __restrict__ x,
                               const float* __restrict__ w0, const float* __restrict__ w1,
                               const float* __restrict__ w2, const float* __restrict__ w3,
                               _Float16* __restrict__ xh, _Float16* __restrict__ wh) {
    int i = blockIdx.x * 256 + threadIdx.x;     // quad index
    const int XQ = NN * DD / 4;                 // 800000 quads of x
    if (i < XQ) {
        float4 v = ((const float4*)x)[i];
        f16x4 o = { (_Float16)v.x, (_Float16)v.y, (_Float16)v.z, (_Float16)v.w };
        ((f16x4*)xh)[i] = o;
    } else {
        int wi = i - XQ;                        // 4 mats * 3072 quads
        if (wi >= 4 * 3072) return;
        int mat = wi / 3072, q = wi - mat * 3072;
        const float* s = mat == 0 ? w0 : mat == 1 ? w1 : mat == 2 ? w2 : w3;
        float4 v = ((const float4*)s)[q];
        f16x4 o = { (_Float16)v.x, (_Float16)v.y, (_Float16)v.z, (_Float16)v.w };
        ((f16x4*)(wh + mat * 12288))[q] = o;
    }
}

// ---------------------------------------------------------------------------
// Scatter: aggr[dst] += x[src] * w.  8 lanes per edge, 8 d-values per lane.
// f32 atomics (native global_atomic_add_f32 via unsafeAtomicAdd).
// ---------------------------------------------------------------------------
__global__ void scatter_kernel(const int* __restrict__ ei, const float* __restrict__ ew,
                               const _Float16* __restrict__ xh, float* __restrict__ aggr) {
    int gid = blockIdx.x * 256 + threadIdx.x;
    int e = gid >> 3;
    if (e >= NE) return;
    int dsub = (gid & 7) << 3;
    int src = ei[e];
    int dst = ei[NE + e];
    float w = ew[e];
    f16x8 v = *(const f16x8*)(xh + src * DD + dsub);   // 16B contiguous per lane
    float* ap = aggr + dst * DD + dsub;
    #pragma unroll
    for (int j = 0; j < 8; ++j) unsafeAtomicAdd(ap + j, (float)v[j] * w);
}

// ---------------------------------------------------------------------------
// Fused GRU cell with fp16 MFMA. One wave per 16-node tile.
//   gi = aggr @ Wih^T (+bih), gh = h @ Whh^T (+bhh)
//   r,z accumulators hold gi+gh (only the sum is needed); n kept split.
// A/B fragments use the SAME k mapping (8 contiguous per lane) -> result exact
// under any HW per-lane k permutation. C/D: col=lane&15, row=(lane>>4)*4+reg.
// ---------------------------------------------------------------------------
__global__ __launch_bounds__(256) void gru_kernel(
    const float* __restrict__ aggr,      // [N,64] f32 (from scatter)
    const _Float16* __restrict__ hA,     // [N,64] fp16: matmul input h (x or h1)
    const float* __restrict__ hOldF,     // optional f32 h (layer1: original x), else null
    const _Float16* __restrict__ wih,    // [192*64] fp16
    const _Float16* __restrict__ whh,    // [192*64] fp16
    const float* __restrict__ bih, const float* __restrict__ bhh,
    float* __restrict__ outF,            // layer2: d_out f32 (or null)
    _Float16* __restrict__ outH)         // layer1: h1 fp16 (or null)
{
    // Weights in LDS, rows padded 64->72 halves (144B: 16B-aligned, 2-way banks = free)
    __shared__ _Float16 W[2 * 192 * 72];
    #pragma unroll
    for (int it = 0; it < 12; ++it) {
        int idx = threadIdx.x + it * 256;          // 3072 vec8 = 2 mats * 192 rows * 8
        int mat = idx >= 1536 ? 1 : 0;
        int lid = idx - mat * 1536;
        int o = lid >> 3, k8 = (lid & 7) << 3;
        f16x8 v = *(const f16x8*)((mat ? whh : wih) + o * 64 + k8);
        *(f16x8*)&W[mat * 13824 + o * 72 + k8] = v;
    }
    __syncthreads();

    int lane = threadIdx.x & 63;
    int tile = blockIdx.x * 4 + (threadIdx.x >> 6);
    if (tile >= NT) return;
    int base = tile << 4;
    int c = lane & 15, g = lane >> 4;

    // A fragments: lane holds row (base+c), k = s*32 + g*8 .. +7
    f16x8 Aa[2], Ah[2];
    {
        const float*    ap = aggr + (base + c) * DD + g * 8;
        const _Float16* hp = hA   + (base + c) * DD + g * 8;
        #pragma unroll
        for (int s = 0; s < 2; ++s) {
            float4 f0 = *(const float4*)(ap + s * 32);
            float4 f1 = *(const float4*)(ap + s * 32 + 4);
            f16x8 t = { (_Float16)f0.x, (_Float16)f0.y, (_Float16)f0.z, (_Float16)f0.w,
                        (_Float16)f1.x, (_Float16)f1.y, (_Float16)f1.z, (_Float16)f1.w };
            Aa[s] = t;
            Ah[s] = *(const f16x8*)(hp + s * 32);
        }
    }

    f32x4 acc[12], hn[4];
    #pragma unroll
    for (int t = 0; t < 12; ++t) acc[t] = f32x4{0.f, 0.f, 0.f, 0.f};
    #pragma unroll
    for (int t = 0; t < 4; ++t) hn[t] = f32x4{0.f, 0.f, 0.f, 0.f};

    // gi for all 12 out-tiles (o = t*16+c)
    #pragma unroll
    for (int t = 0; t < 12; ++t) {
        #pragma unroll
        for (int s = 0; s < 2; ++s) {
            f16x8 b = *(const f16x8*)&W[(t * 16 + c) * 72 + s * 32 + g * 8];
            acc[t] = __builtin_amdgcn_mfma_f32_16x16x32_f16(Aa[s], b, acc[t], 0, 0, 0);
        }
    }
    // gh for r,z tiles (0..7): accumulate into the same acc (only sum needed)
    #pragma unroll
    for (int t = 0; t < 8; ++t) {
        #pragma unroll
        for (int s = 0; s < 2; ++s) {
            f16x8 b = *(const f16x8*)&W[13824 + (t * 16 + c) * 72 + s * 32 + g * 8];
            acc[t] = __builtin_amdgcn_mfma_f32_16x16x32_f16(Ah[s], b, acc[t], 0, 0, 0);
        }
    }
    // gh for n tiles (8..11): separate h_n
    #pragma unroll
    for (int t = 0; t < 4; ++t) {
        #pragma unroll
        for (int s = 0; s < 2; ++s) {
            f16x8 b = *(const f16x8*)&W[13824 + ((t + 8) * 16 + c) * 72 + s * 32 + g * 8];
            hn[t] = __builtin_amdgcn_mfma_f32_16x16x32_f16(Ah[s], b, hn[t], 0, 0, 0);
        }
    }

    // biases (lane-local, d = j*16 + c)
    float br[4], bz[4], bi_[4], bh_[4];
    #pragma unroll
    for (int j = 0; j < 4; ++j) {
        int d = j * 16 + c;
        br[j] = bih[d] + bhh[d];
        bz[j] = bih[64 + d] + bhh[64 + d];
        bi_[j] = bih[128 + d];
        bh_[j] = bhh[128 + d];
    }

    // gates + output. C layout: row (node) = g*4+m, col (d-slot) = c.
    #pragma unroll
    for (int m = 0; m < 4; ++m) {
        int n = base + g * 4 + m;
        #pragma unroll
        for (int j = 0; j < 4; ++j) {
            int d = j * 16 + c;
            float rv = 1.f / (1.f + __expf(-(acc[j][m] + br[j])));
            float zv = 1.f / (1.f + __expf(-(acc[4 + j][m] + bz[j])));
            float nv = tanhf(acc[8 + j][m] + bi_[j] + rv * (hn[j][m] + bh_[j]));
            float hold = hOldF ? hOldF[n * DD + d] : (float)hA[n * DD + d];
            float o = (1.f - zv) * nv + zv * hold;
            if (outF) outF[n * DD + d] = o;
            else      outH[n * DD + d] = (_Float16)o;
        }
    }
}

// ---------------------------------------------------------------------------
extern "C" void kernel_launch(void* const* d_in, const int* in_sizes, int n_in,
                              void* d_out, int out_size, void* d_ws, size_t ws_size,
                              hipStream_t stream) {
    const float* x    = (const float*)d_in[0];
    const int*   ei   = (const int*)d_in[1];     // [2,E] int32
    const float* ew   = (const float*)d_in[2];   // [E,1]
    const float* wih1 = (const float*)d_in[3];
    const float* whh1 = (const float*)d_in[4];
    const float* bih1 = (const float*)d_in[5];
    const float* bhh1 = (const float*)d_in[6];
    const float* wih2 = (const float*)d_in[7];
    const float* whh2 = (const float*)d_in[8];
    const float* bih2 = (const float*)d_in[9];
    const float* bhh2 = (const float*)d_in[10];
    float* out = (float*)d_out;

    // workspace layout (bytes): aggr f32 12.8MB | xh f16 6.4MB | h1h f16 6.4MB | wh f16 96KB
    char* ws = (char*)d_ws;
    float*    aggr = (float*)ws;
    _Float16* xh   = (_Float16*)(ws + 12800000);
    _Float16* h1h  = (_Float16*)(ws + 12800000 + 6400000);
    _Float16* wh   = (_Float16*)(ws + 12800000 + 6400000 + 6400000);

    // convert x + 4 weight mats to fp16: (800000 + 12288) quads / 256 = 3173 blocks
    convert_kernel<<<3173, 256, 0, stream>>>(x, wih1, whh1, wih2, whh2, xh, wh);

    // ---- layer 1 ----
    (void)hipMemsetAsync(aggr, 0, NN * DD * sizeof(float), stream);
    scatter_kernel<<<NE * 8 / 256, 256, 0, stream>>>(ei, ew, xh, aggr);
    gru_kernel<<<(NT + 3) / 4, 256, 0, stream>>>(aggr, xh, x,
                                                 wh, wh + 12288, bih1, bhh1,
                                                 nullptr, h1h);

    // ---- layer 2 ----
    (void)hipMemsetAsync(aggr, 0, NN * DD * sizeof(float), stream);
    scatter_kernel<<<NE * 8 / 256, 256, 0, stream>>>(ei, ew, h1h, aggr);
    gru_kernel<<<(NT + 3) / 4, 256, 0, stream>>>(aggr, h1h, nullptr,
                                                 wh + 2 * 12288, wh + 3 * 12288, bih2, bhh2,
                                                 out, nullptr);
}

// Round 2
// 401.455 us; speedup vs baseline: 7.1861x; 7.1861x over previous
//
#include <hip/hip_runtime.h>

// DCRNN: 2x (CSR-gather SpMM -> fused MFMA GRU cell). N=50000, E=800000, D=64.
#define NN 50000
#define NE 800000
#define DD 64
#define NT (NN / 16)   // 3125 node-tiles of 16

typedef float     f32x4 __attribute__((ext_vector_type(4)));
typedef _Float16  f16x8 __attribute__((ext_vector_type(8)));
typedef _Float16  f16x4 __attribute__((ext_vector_type(4)));

// ---------------------------------------------------------------------------
// Convert x [N,64] f32 -> fp16, and the 4 weight matrices [192][64] -> fp16.
// ---------------------------------------------------------------------------
__global__ void convert_kernel(const float* __restrict__ x,
                               const float* __restrict__ w0, const float* __restrict__ w1,
                               const float* __restrict__ w2, const float* __restrict__ w3,
                               _Float16* __restrict__ xh, _Float16* __restrict__ wh) {
    int i = blockIdx.x * 256 + threadIdx.x;     // quad index
    const int XQ = NN * DD / 4;                 // 800000 quads of x
    if (i < XQ) {
        float4 v = ((const float4*)x)[i];
        f16x4 o = { (_Float16)v.x, (_Float16)v.y, (_Float16)v.z, (_Float16)v.w };
        ((f16x4*)xh)[i] = o;
    } else {
        int wi = i - XQ;                        // 4 mats * 3072 quads
        if (wi >= 4 * 3072) return;
        int mat = wi / 3072, q = wi - mat * 3072;
        const float* s = mat == 0 ? w0 : mat == 1 ? w1 : mat == 2 ? w2 : w3;
        float4 v = ((const float4*)s)[q];
        f16x4 o = { (_Float16)v.x, (_Float16)v.y, (_Float16)v.z, (_Float16)v.w };
        ((f16x4*)(wh + mat * 12288))[q] = o;
    }
}

// ---------------------------------------------------------------------------
// CSR build: histogram by dst -> exclusive scan -> reorder edges to (src,w).
// Only 1.6M cheap int atomics total (vs 102M f32 atomics in the old scatter).
// ---------------------------------------------------------------------------
__global__ void hist_kernel(const int* __restrict__ ei, int* __restrict__ counts) {
    int e = blockIdx.x * 256 + threadIdx.x;
    if (e < NE) atomicAdd(&counts[ei[NE + e]], 1);
}

__global__ void scan_kernel(const int* __restrict__ counts,
                            int* __restrict__ off, int* __restrict__ cursor) {
    __shared__ int part[256];
    int t = threadIdx.x;
    const int CH = (NN + 255) / 256;            // 196 bins per thread
    int lo = t * CH, hi = lo + CH; if (hi > NN) hi = NN;
    int s = 0;
    for (int i = lo; i < hi; ++i) s += counts[i];
    part[t] = s;
    __syncthreads();
    if (t == 0) {
        int run = 0;
        for (int i = 0; i < 256; ++i) { int v = part[i]; part[i] = run; run += v; }
        off[NN] = run;                          // == NE
    }
    __syncthreads();
    int run = part[t];
    for (int i = lo; i < hi; ++i) {
        off[i] = run; cursor[i] = run; run += counts[i];
    }
}

__global__ void reorder_kernel(const int* __restrict__ ei, const float* __restrict__ ew,
                               int* __restrict__ cursor, int2* __restrict__ se) {
    int e = blockIdx.x * 256 + threadIdx.x;
    if (e >= NE) return;
    int dst = ei[NE + e];
    int pos = atomicAdd(&cursor[dst], 1);
    se[pos] = make_int2(ei[e], __float_as_int(ew[e]));
}

// ---------------------------------------------------------------------------
// Aggregation: one wave per node, lane = d-channel. Per edge: one coalesced
// 128B fp16 row gather (L2/LLC-resident) + FMA. No atomics. f32 accumulate,
// fp16 store (aggr only feeds the fp16 MFMA anyway).
// ---------------------------------------------------------------------------
__global__ __launch_bounds__(256) void aggr_kernel(const int* __restrict__ off,
                                                   const int2* __restrict__ se,
                                                   const _Float16* __restrict__ xh,
                                                   _Float16* __restrict__ aggrh) {
    int wv = (blockIdx.x * 256 + threadIdx.x) >> 6;
    if (wv >= NN) return;
    int lane = threadIdx.x & 63;
    int s = off[wv], e = off[wv + 1];
    float acc = 0.f;
    for (int i = s; i < e; ++i) {
        int2 ed = se[i];
        acc += (float)xh[ed.x * DD + lane] * __int_as_float(ed.y);
    }
    aggrh[wv * DD + lane] = (_Float16)acc;
}

// ---------------------------------------------------------------------------
// Fused GRU cell with fp16 MFMA. One wave per 16-node tile.
// A/B fragments use the SAME k mapping (8 contiguous per lane) -> result exact
// under any HW per-lane k permutation. C/D: col=lane&15, row=(lane>>4)*4+reg.
// ---------------------------------------------------------------------------
__global__ __launch_bounds__(256) void gru_kernel(
    const _Float16* __restrict__ aggrh,  // [N,64] fp16 (from aggregation)
    const _Float16* __restrict__ hA,     // [N,64] fp16: matmul input h (x or h1)
    const float* __restrict__ hOldF,     // optional f32 h (layer1: original x), else null
    const _Float16* __restrict__ wih,    // [192*64] fp16
    const _Float16* __restrict__ whh,    // [192*64] fp16
    const float* __restrict__ bih, const float* __restrict__ bhh,
    float* __restrict__ outF,            // layer2: d_out f32 (or null)
    _Float16* __restrict__ outH)         // layer1: h1 fp16 (or null)
{
    // Weights in LDS, rows padded 64->72 halves (144B: 16B-aligned, 2-way banks = free)
    __shared__ _Float16 W[2 * 192 * 72];
    #pragma unroll
    for (int it = 0; it < 12; ++it) {
        int idx = threadIdx.x + it * 256;          // 3072 vec8 = 2 mats * 192 rows * 8
        int mat = idx >= 1536 ? 1 : 0;
        int lid = idx - mat * 1536;
        int o = lid >> 3, k8 = (lid & 7) << 3;
        f16x8 v = *(const f16x8*)((mat ? whh : wih) + o * 64 + k8);
        *(f16x8*)&W[mat * 13824 + o * 72 + k8] = v;
    }
    __syncthreads();

    int lane = threadIdx.x & 63;
    int tile = blockIdx.x * 4 + (threadIdx.x >> 6);
    if (tile >= NT) return;
    int base = tile << 4;
    int c = lane & 15, g = lane >> 4;

    // A fragments: lane holds row (base+c), k = s*32 + g*8 .. +7
    f16x8 Aa[2], Ah[2];
    {
        const _Float16* ap = aggrh + (base + c) * DD + g * 8;
        const _Float16* hp = hA    + (base + c) * DD + g * 8;
        #pragma unroll
        for (int s = 0; s < 2; ++s) {
            Aa[s] = *(const f16x8*)(ap + s * 32);
            Ah[s] = *(const f16x8*)(hp + s * 32);
        }
    }

    f32x4 acc[12], hn[4];
    #pragma unroll
    for (int t = 0; t < 12; ++t) acc[t] = f32x4{0.f, 0.f, 0.f, 0.f};
    #pragma unroll
    for (int t = 0; t < 4; ++t) hn[t] = f32x4{0.f, 0.f, 0.f, 0.f};

    // gi for all 12 out-tiles (o = t*16+c)
    #pragma unroll
    for (int t = 0; t < 12; ++t) {
        #pragma unroll
        for (int s = 0; s < 2; ++s) {
            f16x8 b = *(const f16x8*)&W[(t * 16 + c) * 72 + s * 32 + g * 8];
            acc[t] = __builtin_amdgcn_mfma_f32_16x16x32_f16(Aa[s], b, acc[t], 0, 0, 0);
        }
    }
    // gh for r,z tiles (0..7): accumulate into the same acc (only sum needed)
    #pragma unroll
    for (int t = 0; t < 8; ++t) {
        #pragma unroll
        for (int s = 0; s < 2; ++s) {
            f16x8 b = *(const f16x8*)&W[13824 + (t * 16 + c) * 72 + s * 32 + g * 8];
            acc[t] = __builtin_amdgcn_mfma_f32_16x16x32_f16(Ah[s], b, acc[t], 0, 0, 0);
        }
    }
    // gh for n tiles (8..11): separate h_n
    #pragma unroll
    for (int t = 0; t < 4; ++t) {
        #pragma unroll
        for (int s = 0; s < 2; ++s) {
            f16x8 b = *(const f16x8*)&W[13824 + ((t + 8) * 16 + c) * 72 + s * 32 + g * 8];
            hn[t] = __builtin_amdgcn_mfma_f32_16x16x32_f16(Ah[s], b, hn[t], 0, 0, 0);
        }
    }

    // biases (lane-local, d = j*16 + c)
    float br[4], bz[4], bi_[4], bh_[4];
    #pragma unroll
    for (int j = 0; j < 4; ++j) {
        int d = j * 16 + c;
        br[j] = bih[d] + bhh[d];
        bz[j] = bih[64 + d] + bhh[64 + d];
        bi_[j] = bih[128 + d];
        bh_[j] = bhh[128 + d];
    }

    // gates + output. C layout: row (node) = g*4+m, col (d-slot) = c.
    #pragma unroll
    for (int m = 0; m < 4; ++m) {
        int n = base + g * 4 + m;
        #pragma unroll
        for (int j = 0; j < 4; ++j) {
            int d = j * 16 + c;
            float rv = 1.f / (1.f + __expf(-(acc[j][m] + br[j])));
            float zv = 1.f / (1.f + __expf(-(acc[4 + j][m] + bz[j])));
            float nv = tanhf(acc[8 + j][m] + bi_[j] + rv * (hn[j][m] + bh_[j]));
            float hold = hOldF ? hOldF[n * DD + d] : (float)hA[n * DD + d];
            float o = (1.f - zv) * nv + zv * hold;
            if (outF) outF[n * DD + d] = o;
            else      outH[n * DD + d] = (_Float16)o;
        }
    }
}

// ---------------------------------------------------------------------------
extern "C" void kernel_launch(void* const* d_in, const int* in_sizes, int n_in,
                              void* d_out, int out_size, void* d_ws, size_t ws_size,
                              hipStream_t stream) {
    const float* x    = (const float*)d_in[0];
    const int*   ei   = (const int*)d_in[1];     // [2,E] int32
    const float* ew   = (const float*)d_in[2];   // [E,1]
    const float* wih1 = (const float*)d_in[3];
    const float* whh1 = (const float*)d_in[4];
    const float* bih1 = (const float*)d_in[5];
    const float* bhh1 = (const float*)d_in[6];
    const float* wih2 = (const float*)d_in[7];
    const float* whh2 = (const float*)d_in[8];
    const float* bih2 = (const float*)d_in[9];
    const float* bhh2 = (const float*)d_in[10];
    float* out = (float*)d_out;

    // workspace layout (bytes):
    //   xh 6.4MB | h1h 6.4MB | aggrh 6.4MB | se 6.4MB | wh 96KB | counts/off/cursor 600KB
    char* ws = (char*)d_ws;
    _Float16* xh     = (_Float16*)ws;
    _Float16* h1h    = (_Float16*)(ws + 6400000);
    _Float16* aggrh  = (_Float16*)(ws + 12800000);
    int2*     se     = (int2*)    (ws + 19200000);
    _Float16* wh     = (_Float16*)(ws + 25600000);
    int*      counts = (int*)     (ws + 25700000);
    int*      off    = (int*)     (ws + 25900004);
    int*      cursor = (int*)     (ws + 26100008);

    // convert x + 4 weight mats to fp16; zero histogram bins
    convert_kernel<<<3173, 256, 0, stream>>>(x, wih1, whh1, wih2, whh2, xh, wh);
    (void)hipMemsetAsync(counts, 0, NN * sizeof(int), stream);

    // CSR build (edge_index shared by both layers)
    hist_kernel<<<NE / 256, 256, 0, stream>>>(ei, counts);
    scan_kernel<<<1, 256, 0, stream>>>(counts, off, cursor);
    reorder_kernel<<<NE / 256, 256, 0, stream>>>(ei, ew, cursor, se);

    // ---- layer 1 ----
    aggr_kernel<<<NN * 64 / 256, 256, 0, stream>>>(off, se, xh, aggrh);
    gru_kernel<<<(NT + 3) / 4, 256, 0, stream>>>(aggrh, xh, x,
                                                 wh, wh + 12288, bih1, bhh1,
                                                 nullptr, h1h);

    // ---- layer 2 ----
    aggr_kernel<<<NN * 64 / 256, 256, 0, stream>>>(off, se, h1h, aggrh);
    gru_kernel<<<(NT + 3) / 4, 256, 0, stream>>>(aggrh, h1h, nullptr,
                                                 wh + 2 * 12288, wh + 3 * 12288, bih2, bhh2,
                                                 out, nullptr);
}

// Round 3
// 233.945 us; speedup vs baseline: 12.3315x; 1.7160x over previous
//
#include <hip/hip_runtime.h>

// DCRNN: 2x (CSR-gather SpMM -> fused MFMA GRU cell). N=50000, E=800000, D=64.
#define NN 50000
#define NE 800000
#define DD 64
#define NT (NN / 16)   // 3125 node-tiles of 16
#define NB 196         // scan blocks: 196*256 = 50176 >= NN

typedef float     f32x4 __attribute__((ext_vector_type(4)));
typedef _Float16  f16x8 __attribute__((ext_vector_type(8)));
typedef _Float16  f16x4 __attribute__((ext_vector_type(4)));

// ---------------------------------------------------------------------------
// Fused: convert x [N,64] f32 -> fp16 + 4 weight mats -> fp16  ||  dst histogram.
// (independent work, one launch)
// ---------------------------------------------------------------------------
__global__ void conv_hist_kernel(const float* __restrict__ x,
                                 const float* __restrict__ w0, const float* __restrict__ w1,
                                 const float* __restrict__ w2, const float* __restrict__ w3,
                                 _Float16* __restrict__ xh, _Float16* __restrict__ wh,
                                 const int* __restrict__ ei, int* __restrict__ counts) {
    const int CONV_BLOCKS = 3173;               // (800000 + 12288 quads) / 256
    if (blockIdx.x < CONV_BLOCKS) {
        int i = blockIdx.x * 256 + threadIdx.x; // quad index
        const int XQ = NN * DD / 4;             // 800000 quads of x
        if (i < XQ) {
            float4 v = ((const float4*)x)[i];
            f16x4 o = { (_Float16)v.x, (_Float16)v.y, (_Float16)v.z, (_Float16)v.w };
            ((f16x4*)xh)[i] = o;
        } else {
            int wi = i - XQ;                    // 4 mats * 3072 quads
            if (wi >= 4 * 3072) return;
            int mat = wi / 3072, q = wi - mat * 3072;
            const float* s = mat == 0 ? w0 : mat == 1 ? w1 : mat == 2 ? w2 : w3;
            float4 v = ((const float4*)s)[q];
            f16x4 o = { (_Float16)v.x, (_Float16)v.y, (_Float16)v.z, (_Float16)v.w };
            ((f16x4*)(wh + mat * 12288))[q] = o;
        }
    } else {
        int e = (blockIdx.x - CONV_BLOCKS) * 256 + threadIdx.x;
        if (e < NE) atomicAdd(&counts[ei[NE + e]], 1);
    }
}

// ---------------------------------------------------------------------------
// Parallel exclusive scan of counts[NN] -> off[NN+1], cursor[NN].
// ---------------------------------------------------------------------------
__global__ void scan1_kernel(const int* __restrict__ counts, int* __restrict__ bsum) {
    __shared__ int red[256];
    int i = blockIdx.x * 256 + threadIdx.x;
    int v = (i < NN) ? counts[i] : 0;
    red[threadIdx.x] = v;
    __syncthreads();
    for (int d = 128; d > 0; d >>= 1) {
        if (threadIdx.x < d) red[threadIdx.x] += red[threadIdx.x + d];
        __syncthreads();
    }
    if (threadIdx.x == 0) bsum[blockIdx.x] = red[0];
}

__global__ void scan2_kernel(const int* __restrict__ bsum, int* __restrict__ bofs,
                             int* __restrict__ off) {
    __shared__ int tmp[256];
    int t = threadIdx.x;
    int v = (t < NB) ? bsum[t] : 0;
    tmp[t] = v;
    __syncthreads();
    #pragma unroll
    for (int d = 1; d < 256; d <<= 1) {
        int add = (t >= d) ? tmp[t - d] : 0;
        __syncthreads();
        tmp[t] += add;
        __syncthreads();
    }
    if (t < NB) bofs[t] = tmp[t] - v;           // exclusive
    if (t == 255) off[NN] = tmp[255];           // total == NE
}

__global__ void scan3_kernel(const int* __restrict__ counts, const int* __restrict__ bofs,
                             int* __restrict__ off, int* __restrict__ cursor) {
    __shared__ int tmp[256];
    int t = threadIdx.x;
    int i = blockIdx.x * 256 + t;
    int v = (i < NN) ? counts[i] : 0;
    tmp[t] = v;
    __syncthreads();
    #pragma unroll
    for (int d = 1; d < 256; d <<= 1) {
        int add = (t >= d) ? tmp[t - d] : 0;
        __syncthreads();
        tmp[t] += add;
        __syncthreads();
    }
    if (i < NN) {
        int exc = bofs[blockIdx.x] + tmp[t] - v;
        off[i] = exc;
        cursor[i] = exc;
    }
}

__global__ void reorder_kernel(const int* __restrict__ ei, const float* __restrict__ ew,
                               int* __restrict__ cursor, int2* __restrict__ se) {
    int e = blockIdx.x * 256 + threadIdx.x;
    if (e >= NE) return;
    int dst = ei[NE + e];
    int pos = atomicAdd(&cursor[dst], 1);
    se[pos] = make_int2(ei[e], __float_as_int(ew[e]));
}

// ---------------------------------------------------------------------------
// Aggregation: one wave per node, lane = d-channel. Per edge: one coalesced
// 128B fp16 row gather (LLC-resident) + FMA. No atomics. 2-deep unroll for
// load ILP (acc is the only loop-carried dep).
// ---------------------------------------------------------------------------
__global__ __launch_bounds__(256) void aggr_kernel(const int* __restrict__ off,
                                                   const int2* __restrict__ se,
                                                   const _Float16* __restrict__ xh,
                                                   _Float16* __restrict__ aggrh) {
    int wv = (blockIdx.x * 256 + threadIdx.x) >> 6;
    if (wv >= NN) return;
    int lane = threadIdx.x & 63;
    int s = off[wv], e = off[wv + 1];
    float acc = 0.f;
    int i = s;
    for (; i + 1 < e; i += 2) {
        int2 e0 = se[i], e1 = se[i + 1];
        float a0 = (float)xh[e0.x * DD + lane];
        float a1 = (float)xh[e1.x * DD + lane];
        acc += a0 * __int_as_float(e0.y);
        acc += a1 * __int_as_float(e1.y);
    }
    if (i < e) {
        int2 ed = se[i];
        acc += (float)xh[ed.x * DD + lane] * __int_as_float(ed.y);
    }
    aggrh[wv * DD + lane] = (_Float16)acc;
}

// ---------------------------------------------------------------------------
// Fused GRU cell with fp16 MFMA. One wave per 16-node tile.
// A/B fragments use the SAME k mapping (8 contiguous per lane) -> result exact
// under any HW per-lane k permutation. C/D: col=lane&15, row=(lane>>4)*4+reg.
// ---------------------------------------------------------------------------
__global__ __launch_bounds__(256) void gru_kernel(
    const _Float16* __restrict__ aggrh,  // [N,64] fp16 (from aggregation)
    const _Float16* __restrict__ hA,     // [N,64] fp16: matmul input h (x or h1)
    const float* __restrict__ hOldF,     // optional f32 h (layer1: original x), else null
    const _Float16* __restrict__ wih,    // [192*64] fp16
    const _Float16* __restrict__ whh,    // [192*64] fp16
    const float* __restrict__ bih, const float* __restrict__ bhh,
    float* __restrict__ outF,            // layer2: d_out f32 (or null)
    _Float16* __restrict__ outH)         // layer1: h1 fp16 (or null)
{
    // Weights in LDS, rows padded 64->72 halves (144B: 16B-aligned, 2-way banks = free)
    __shared__ _Float16 W[2 * 192 * 72];
    #pragma unroll
    for (int it = 0; it < 12; ++it) {
        int idx = threadIdx.x + it * 256;          // 3072 vec8 = 2 mats * 192 rows * 8
        int mat = idx >= 1536 ? 1 : 0;
        int lid = idx - mat * 1536;
        int o = lid >> 3, k8 = (lid & 7) << 3;
        f16x8 v = *(const f16x8*)((mat ? whh : wih) + o * 64 + k8);
        *(f16x8*)&W[mat * 13824 + o * 72 + k8] = v;
    }
    __syncthreads();

    int lane = threadIdx.x & 63;
    int tile = blockIdx.x * 4 + (threadIdx.x >> 6);
    if (tile >= NT) return;
    int base = tile << 4;
    int c = lane & 15, g = lane >> 4;

    // A fragments: lane holds row (base+c), k = s*32 + g*8 .. +7
    f16x8 Aa[2], Ah[2];
    {
        const _Float16* ap = aggrh + (base + c) * DD + g * 8;
        const _Float16* hp = hA    + (base + c) * DD + g * 8;
        #pragma unroll
        for (int s = 0; s < 2; ++s) {
            Aa[s] = *(const f16x8*)(ap + s * 32);
            Ah[s] = *(const f16x8*)(hp + s * 32);
        }
    }

    f32x4 acc[12], hn[4];
    #pragma unroll
    for (int t = 0; t < 12; ++t) acc[t] = f32x4{0.f, 0.f, 0.f, 0.f};
    #pragma unroll
    for (int t = 0; t < 4; ++t) hn[t] = f32x4{0.f, 0.f, 0.f, 0.f};

    // gi for all 12 out-tiles (o = t*16+c)
    #pragma unroll
    for (int t = 0; t < 12; ++t) {
        #pragma unroll
        for (int s = 0; s < 2; ++s) {
            f16x8 b = *(const f16x8*)&W[(t * 16 + c) * 72 + s * 32 + g * 8];
            acc[t] = __builtin_amdgcn_mfma_f32_16x16x32_f16(Aa[s], b, acc[t], 0, 0, 0);
        }
    }
    // gh for r,z tiles (0..7): accumulate into the same acc (only sum needed)
    #pragma unroll
    for (int t = 0; t < 8; ++t) {
        #pragma unroll
        for (int s = 0; s < 2; ++s) {
            f16x8 b = *(const f16x8*)&W[13824 + (t * 16 + c) * 72 + s * 32 + g * 8];
            acc[t] = __builtin_amdgcn_mfma_f32_16x16x32_f16(Ah[s], b, acc[t], 0, 0, 0);
        }
    }
    // gh for n tiles (8..11): separate h_n
    #pragma unroll
    for (int t = 0; t < 4; ++t) {
        #pragma unroll
        for (int s = 0; s < 2; ++s) {
            f16x8 b = *(const f16x8*)&W[13824 + ((t + 8) * 16 + c) * 72 + s * 32 + g * 8];
            hn[t] = __builtin_amdgcn_mfma_f32_16x16x32_f16(Ah[s], b, hn[t], 0, 0, 0);
        }
    }

    // biases (lane-local, d = j*16 + c)
    float br[4], bz[4], bi_[4], bh_[4];
    #pragma unroll
    for (int j = 0; j < 4; ++j) {
        int d = j * 16 + c;
        br[j] = bih[d] + bhh[d];
        bz[j] = bih[64 + d] + bhh[64 + d];
        bi_[j] = bih[128 + d];
        bh_[j] = bhh[128 + d];
    }

    // gates + output. C layout: row (node) = g*4+m, col (d-slot) = c.
    #pragma unroll
    for (int m = 0; m < 4; ++m) {
        int n = base + g * 4 + m;
        #pragma unroll
        for (int j = 0; j < 4; ++j) {
            int d = j * 16 + c;
            float rv = 1.f / (1.f + __expf(-(acc[j][m] + br[j])));
            float zv = 1.f / (1.f + __expf(-(acc[4 + j][m] + bz[j])));
            float nv = tanhf(acc[8 + j][m] + bi_[j] + rv * (hn[j][m] + bh_[j]));
            float hold = hOldF ? hOldF[n * DD + d] : (float)hA[n * DD + d];
            float o = (1.f - zv) * nv + zv * hold;
            if (outF) outF[n * DD + d] = o;
            else      outH[n * DD + d] = (_Float16)o;
        }
    }
}

// ---------------------------------------------------------------------------
extern "C" void kernel_launch(void* const* d_in, const int* in_sizes, int n_in,
                              void* d_out, int out_size, void* d_ws, size_t ws_size,
                              hipStream_t stream) {
    const float* x    = (const float*)d_in[0];
    const int*   ei   = (const int*)d_in[1];     // [2,E] int32
    const float* ew   = (const float*)d_in[2];   // [E,1]
    const float* wih1 = (const float*)d_in[3];
    const float* whh1 = (const float*)d_in[4];
    const float* bih1 = (const float*)d_in[5];
    const float* bhh1 = (const float*)d_in[6];
    const float* wih2 = (const float*)d_in[7];
    const float* whh2 = (const float*)d_in[8];
    const float* bih2 = (const float*)d_in[9];
    const float* bhh2 = (const float*)d_in[10];
    float* out = (float*)d_out;

    // workspace layout (bytes):
    //   xh 6.4MB | h1h 6.4MB | aggrh 6.4MB | se 6.4MB | wh 96KB
    //   counts 200KB | off 200KB | cursor 200KB | bsum/bofs ~2KB
    char* ws = (char*)d_ws;
    _Float16* xh     = (_Float16*)ws;
    _Float16* h1h    = (_Float16*)(ws + 6400000);
    _Float16* aggrh  = (_Float16*)(ws + 12800000);
    int2*     se     = (int2*)    (ws + 19200000);
    _Float16* wh     = (_Float16*)(ws + 25600000);
    int*      counts = (int*)     (ws + 25700000);
    int*      off    = (int*)     (ws + 25900004);
    int*      cursor = (int*)     (ws + 26100008);
    int*      bsum   = (int*)     (ws + 26300012);
    int*      bofs   = (int*)     (ws + 26301012);

    (void)hipMemsetAsync(counts, 0, NN * sizeof(int), stream);

    // convert (x + weights -> fp16) || histogram, one launch
    conv_hist_kernel<<<3173 + 3125, 256, 0, stream>>>(x, wih1, whh1, wih2, whh2, xh, wh,
                                                      ei, counts);
    // parallel scan -> off/cursor
    scan1_kernel<<<NB, 256, 0, stream>>>(counts, bsum);
    scan2_kernel<<<1, 256, 0, stream>>>(bsum, bofs, off);
    scan3_kernel<<<NB, 256, 0, stream>>>(counts, bofs, off, cursor);
    reorder_kernel<<<NE / 256, 256, 0, stream>>>(ei, ew, cursor, se);

    // ---- layer 1 ----
    aggr_kernel<<<NN * 64 / 256, 256, 0, stream>>>(off, se, xh, aggrh);
    gru_kernel<<<(NT + 3) / 4, 256, 0, stream>>>(aggrh, xh, x,
                                                 wh, wh + 12288, bih1, bhh1,
                                                 nullptr, h1h);

    // ---- layer 2 ----
    aggr_kernel<<<NN * 64 / 256, 256, 0, stream>>>(off, se, h1h, aggrh);
    gru_kernel<<<(NT + 3) / 4, 256, 0, stream>>>(aggrh, h1h, nullptr,
                                                 wh + 2 * 12288, wh + 3 * 12288, bih2, bhh2,
                                                 out, nullptr);
}

// Round 4
// 222.181 us; speedup vs baseline: 12.9844x; 1.0529x over previous
//
#include <hip/hip_runtime.h>

// DCRNN: 2x (CSR-gather SpMM -> fused MFMA GRU cell). N=50000, E=800000, D=64.
#define NN 50000
#define NE 800000
#define DD 64
#define NT (NN / 16)     // 3125 node-tiles of 16
#define NB 196           // scan blocks: 196*256 = 50176 >= NN
#define NPART 8          // dst partitions ~ XCDs
#define PSIZE (NN / NPART)        // 6250 nodes per partition
#define NCHUNK 128                // edge chunks per partition
#define ECHUNK (NE / NCHUNK)      // 6250 edges per chunk

typedef float     f32x4 __attribute__((ext_vector_type(4)));
typedef _Float16  f16x8 __attribute__((ext_vector_type(8)));
typedef _Float16  f16x4 __attribute__((ext_vector_type(4)));

// ---------------------------------------------------------------------------
// Fused: convert x [N,64] f32 -> fp16 + 4 weight mats -> fp16  ||  partitioned
// dst histogram (XCD-local atomics: block b -> partition (b&7) via round-robin
// blockIdx->XCD dispatch; each partition scans all dst, keeps its range).
// ---------------------------------------------------------------------------
__global__ void conv_hist_kernel(const float* __restrict__ x,
                                 const float* __restrict__ w0, const float* __restrict__ w1,
                                 const float* __restrict__ w2, const float* __restrict__ w3,
                                 _Float16* __restrict__ xh, _Float16* __restrict__ wh,
                                 const int* __restrict__ ei, int* __restrict__ counts) {
    const int CONV_BLOCKS = 3173;               // (800000 + 12288 quads) / 256
    if (blockIdx.x < CONV_BLOCKS) {
        int i = blockIdx.x * 256 + threadIdx.x; // quad index
        const int XQ = NN * DD / 4;             // 800000 quads of x
        if (i < XQ) {
            float4 v = ((const float4*)x)[i];
            f16x4 o = { (_Float16)v.x, (_Float16)v.y, (_Float16)v.z, (_Float16)v.w };
            ((f16x4*)xh)[i] = o;
        } else {
            int wi = i - XQ;                    // 4 mats * 3072 quads
            if (wi >= 4 * 3072) return;
            int mat = wi / 3072, q = wi - mat * 3072;
            const float* s = mat == 0 ? w0 : mat == 1 ? w1 : mat == 2 ? w2 : w3;
            float4 v = ((const float4*)s)[q];
            f16x4 o = { (_Float16)v.x, (_Float16)v.y, (_Float16)v.z, (_Float16)v.w };
            ((f16x4*)(wh + mat * 12288))[q] = o;
        }
    } else {
        int part = blockIdx.x & 7;              // ~XCD id (round-robin dispatch)
        int chunk = (blockIdx.x - CONV_BLOCKS) >> 3;
        int dlo = part * PSIZE, dhi = dlo + PSIZE;
        int base = chunk * ECHUNK;
        for (int i = threadIdx.x; i < ECHUNK; i += 256) {
            int dst = ei[NE + base + i];
            if (dst >= dlo && dst < dhi) atomicAdd(&counts[dst], 1);
        }
    }
}

// ---------------------------------------------------------------------------
// Parallel exclusive scan of counts[NN] -> off[NN+1], cursor[NN].
// ---------------------------------------------------------------------------
__global__ void scan1_kernel(const int* __restrict__ counts, int* __restrict__ bsum) {
    __shared__ int red[256];
    int i = blockIdx.x * 256 + threadIdx.x;
    int v = (i < NN) ? counts[i] : 0;
    red[threadIdx.x] = v;
    __syncthreads();
    for (int d = 128; d > 0; d >>= 1) {
        if (threadIdx.x < d) red[threadIdx.x] += red[threadIdx.x + d];
        __syncthreads();
    }
    if (threadIdx.x == 0) bsum[blockIdx.x] = red[0];
}

__global__ void scan2_kernel(const int* __restrict__ bsum, int* __restrict__ bofs,
                             int* __restrict__ off) {
    __shared__ int tmp[256];
    int t = threadIdx.x;
    int v = (t < NB) ? bsum[t] : 0;
    tmp[t] = v;
    __syncthreads();
    #pragma unroll
    for (int d = 1; d < 256; d <<= 1) {
        int add = (t >= d) ? tmp[t - d] : 0;
        __syncthreads();
        tmp[t] += add;
        __syncthreads();
    }
    if (t < NB) bofs[t] = tmp[t] - v;           // exclusive
    if (t == 255) off[NN] = tmp[255];           // total == NE
}

__global__ void scan3_kernel(const int* __restrict__ counts, const int* __restrict__ bofs,
                             int* __restrict__ off, int* __restrict__ cursor) {
    __shared__ int tmp[256];
    int t = threadIdx.x;
    int i = blockIdx.x * 256 + t;
    int v = (i < NN) ? counts[i] : 0;
    tmp[t] = v;
    __syncthreads();
    #pragma unroll
    for (int d = 1; d < 256; d <<= 1) {
        int add = (t >= d) ? tmp[t - d] : 0;
        __syncthreads();
        tmp[t] += add;
        __syncthreads();
    }
    if (i < NN) {
        int exc = bofs[blockIdx.x] + tmp[t] - v;
        off[i] = exc;
        cursor[i] = exc;
    }
}

// ---------------------------------------------------------------------------
// Partitioned reorder: block b -> dst partition (b&7), edge chunk (b>>3).
// Each partition's se region (~800KB) + cursor slice (~25KB) stay in its
// XCD's L2 -> scattered writes stop thrashing lines cross-XCD.
// ---------------------------------------------------------------------------
__global__ void reorder_kernel(const int* __restrict__ ei, const float* __restrict__ ew,
                               int* __restrict__ cursor, int2* __restrict__ se) {
    int part = blockIdx.x & 7;
    int chunk = blockIdx.x >> 3;
    int dlo = part * PSIZE, dhi = dlo + PSIZE;
    int base = chunk * ECHUNK;
    for (int i = threadIdx.x; i < ECHUNK; i += 256) {
        int e = base + i;
        int dst = ei[NE + e];
        if (dst >= dlo && dst < dhi) {
            int pos = atomicAdd(&cursor[dst], 1);
            se[pos] = make_int2(ei[e], __float_as_int(ew[e]));
        }
    }
}

// ---------------------------------------------------------------------------
// Aggregation: one wave per node, lane = d-channel. Per edge: one coalesced
// 128B fp16 row gather (L2/LLC-resident) + FMA. No atomics. 2-deep unroll for
// load ILP (acc is the only loop-carried dep).
// ---------------------------------------------------------------------------
__global__ __launch_bounds__(256) void aggr_kernel(const int* __restrict__ off,
                                                   const int2* __restrict__ se,
                                                   const _Float16* __restrict__ xh,
                                                   _Float16* __restrict__ aggrh) {
    int wv = (blockIdx.x * 256 + threadIdx.x) >> 6;
    if (wv >= NN) return;
    int lane = threadIdx.x & 63;
    int s = off[wv], e = off[wv + 1];
    float acc = 0.f;
    int i = s;
    for (; i + 1 < e; i += 2) {
        int2 e0 = se[i], e1 = se[i + 1];
        float a0 = (float)xh[e0.x * DD + lane];
        float a1 = (float)xh[e1.x * DD + lane];
        acc += a0 * __int_as_float(e0.y);
        acc += a1 * __int_as_float(e1.y);
    }
    if (i < e) {
        int2 ed = se[i];
        acc += (float)xh[ed.x * DD + lane] * __int_as_float(ed.y);
    }
    aggrh[wv * DD + lane] = (_Float16)acc;
}

// ---------------------------------------------------------------------------
// Fused GRU cell with fp16 MFMA. One wave per 16-node tile.
// A/B fragments use the SAME k mapping (8 contiguous per lane) -> result exact
// under any HW per-lane k permutation. C/D: col=lane&15, row=(lane>>4)*4+reg.
// h_old is read from the fp16 hA array (<=2^-11 relative rounding, well
// within threshold margin) -> no f32 x re-read.
// ---------------------------------------------------------------------------
__global__ __launch_bounds__(256) void gru_kernel(
    const _Float16* __restrict__ aggrh,  // [N,64] fp16 (from aggregation)
    const _Float16* __restrict__ hA,     // [N,64] fp16: h (x or h1)
    const _Float16* __restrict__ wih,    // [192*64] fp16
    const _Float16* __restrict__ whh,    // [192*64] fp16
    const float* __restrict__ bih, const float* __restrict__ bhh,
    float* __restrict__ outF,            // layer2: d_out f32 (or null)
    _Float16* __restrict__ outH)         // layer1: h1 fp16 (or null)
{
    // Weights in LDS, rows padded 64->72 halves (144B: 16B-aligned, 2-way banks = free)
    __shared__ _Float16 W[2 * 192 * 72];
    #pragma unroll
    for (int it = 0; it < 12; ++it) {
        int idx = threadIdx.x + it * 256;          // 3072 vec8 = 2 mats * 192 rows * 8
        int mat = idx >= 1536 ? 1 : 0;
        int lid = idx - mat * 1536;
        int o = lid >> 3, k8 = (lid & 7) << 3;
        f16x8 v = *(const f16x8*)((mat ? whh : wih) + o * 64 + k8);
        *(f16x8*)&W[mat * 13824 + o * 72 + k8] = v;
    }
    __syncthreads();

    int lane = threadIdx.x & 63;
    int tile = blockIdx.x * 4 + (threadIdx.x >> 6);
    if (tile >= NT) return;
    int base = tile << 4;
    int c = lane & 15, g = lane >> 4;

    // A fragments: lane holds row (base+c), k = s*32 + g*8 .. +7
    f16x8 Aa[2], Ah[2];
    {
        const _Float16* ap = aggrh + (base + c) * DD + g * 8;
        const _Float16* hp = hA    + (base + c) * DD + g * 8;
        #pragma unroll
        for (int s = 0; s < 2; ++s) {
            Aa[s] = *(const f16x8*)(ap + s * 32);
            Ah[s] = *(const f16x8*)(hp + s * 32);
        }
    }

    f32x4 acc[12], hn[4];
    #pragma unroll
    for (int t = 0; t < 12; ++t) acc[t] = f32x4{0.f, 0.f, 0.f, 0.f};
    #pragma unroll
    for (int t = 0; t < 4; ++t) hn[t] = f32x4{0.f, 0.f, 0.f, 0.f};

    // gi for all 12 out-tiles (o = t*16+c)
    #pragma unroll
    for (int t = 0; t < 12; ++t) {
        #pragma unroll
        for (int s = 0; s < 2; ++s) {
            f16x8 b = *(const f16x8*)&W[(t * 16 + c) * 72 + s * 32 + g * 8];
            acc[t] = __builtin_amdgcn_mfma_f32_16x16x32_f16(Aa[s], b, acc[t], 0, 0, 0);
        }
    }
    // gh for r,z tiles (0..7): accumulate into the same acc (only sum needed)
    #pragma unroll
    for (int t = 0; t < 8; ++t) {
        #pragma unroll
        for (int s = 0; s < 2; ++s) {
            f16x8 b = *(const f16x8*)&W[13824 + (t * 16 + c) * 72 + s * 32 + g * 8];
            acc[t] = __builtin_amdgcn_mfma_f32_16x16x32_f16(Ah[s], b, acc[t], 0, 0, 0);
        }
    }
    // gh for n tiles (8..11): separate h_n
    #pragma unroll
    for (int t = 0; t < 4; ++t) {
        #pragma unroll
        for (int s = 0; s < 2; ++s) {
            f16x8 b = *(const f16x8*)&W[13824 + ((t + 8) * 16 + c) * 72 + s * 32 + g * 8];
            hn[t] = __builtin_amdgcn_mfma_f32_16x16x32_f16(Ah[s], b, hn[t], 0, 0, 0);
        }
    }

    // biases (lane-local, d = j*16 + c)
    float br[4], bz[4], bi_[4], bh_[4];
    #pragma unroll
    for (int j = 0; j < 4; ++j) {
        int d = j * 16 + c;
        br[j] = bih[d] + bhh[d];
        bz[j] = bih[64 + d] + bhh[64 + d];
        bi_[j] = bih[128 + d];
        bh_[j] = bhh[128 + d];
    }

    // gates + output. C layout: row (node) = g*4+m, col (d-slot) = c.
    #pragma unroll
    for (int m = 0; m < 4; ++m) {
        int n = base + g * 4 + m;
        #pragma unroll
        for (int j = 0; j < 4; ++j) {
            int d = j * 16 + c;
            float rv = 1.f / (1.f + __expf(-(acc[j][m] + br[j])));
            float zv = 1.f / (1.f + __expf(-(acc[4 + j][m] + bz[j])));
            float nv = tanhf(acc[8 + j][m] + bi_[j] + rv * (hn[j][m] + bh_[j]));
            float hold = (float)hA[n * DD + d];
            float o = (1.f - zv) * nv + zv * hold;
            if (outF) outF[n * DD + d] = o;
            else      outH[n * DD + d] = (_Float16)o;
        }
    }
}

// ---------------------------------------------------------------------------
extern "C" void kernel_launch(void* const* d_in, const int* in_sizes, int n_in,
                              void* d_out, int out_size, void* d_ws, size_t ws_size,
                              hipStream_t stream) {
    const float* x    = (const float*)d_in[0];
    const int*   ei   = (const int*)d_in[1];     // [2,E] int32
    const float* ew   = (const float*)d_in[2];   // [E,1]
    const float* wih1 = (const float*)d_in[3];
    const float* whh1 = (const float*)d_in[4];
    const float* bih1 = (const float*)d_in[5];
    const float* bhh1 = (const float*)d_in[6];
    const float* wih2 = (const float*)d_in[7];
    const float* whh2 = (const float*)d_in[8];
    const float* bih2 = (const float*)d_in[9];
    const float* bhh2 = (const float*)d_in[10];
    float* out = (float*)d_out;

    // workspace layout (bytes):
    //   xh 6.4MB | h1h 6.4MB | aggrh 6.4MB | se 6.4MB | wh 96KB
    //   counts 200KB | off 200KB | cursor 200KB | bsum/bofs ~2KB
    char* ws = (char*)d_ws;
    _Float16* xh     = (_Float16*)ws;
    _Float16* h1h    = (_Float16*)(ws + 6400000);
    _Float16* aggrh  = (_Float16*)(ws + 12800000);
    int2*     se     = (int2*)    (ws + 19200000);
    _Float16* wh     = (_Float16*)(ws + 25600000);
    int*      counts = (int*)     (ws + 25700000);
    int*      off    = (int*)     (ws + 25900004);
    int*      cursor = (int*)     (ws + 26100008);
    int*      bsum   = (int*)     (ws + 26300012);
    int*      bofs   = (int*)     (ws + 26301012);

    (void)hipMemsetAsync(counts, 0, NN * sizeof(int), stream);

    // convert (x + weights -> fp16) || partitioned histogram, one launch
    conv_hist_kernel<<<3173 + NPART * NCHUNK, 256, 0, stream>>>(
        x, wih1, whh1, wih2, whh2, xh, wh, ei, counts);
    // parallel scan -> off/cursor
    scan1_kernel<<<NB, 256, 0, stream>>>(counts, bsum);
    scan2_kernel<<<1, 256, 0, stream>>>(bsum, bofs, off);
    scan3_kernel<<<NB, 256, 0, stream>>>(counts, bofs, off, cursor);
    // partitioned reorder (XCD-local scatter)
    reorder_kernel<<<NPART * NCHUNK, 256, 0, stream>>>(ei, ew, cursor, se);

    // ---- layer 1 ----
    aggr_kernel<<<NN * 64 / 256, 256, 0, stream>>>(off, se, xh, aggrh);
    gru_kernel<<<(NT + 3) / 4, 256, 0, stream>>>(aggrh, xh,
                                                 wh, wh + 12288, bih1, bhh1,
                                                 nullptr, h1h);

    // ---- layer 2 ----
    aggr_kernel<<<NN * 64 / 256, 256, 0, stream>>>(off, se, h1h, aggrh);
    gru_kernel<<<(NT + 3) / 4, 256, 0, stream>>>(aggrh, h1h,
                                                 wh + 2 * 12288, wh + 3 * 12288, bih2, bhh2,
                                                 out, nullptr);
}

// Round 5
// 183.019 us; speedup vs baseline: 15.7628x; 1.2140x over previous
//
#include <hip/hip_runtime.h>

// DCRNN: 2x (CSR-gather SpMM -> fused MFMA GRU cell). N=50000, E=800000, D=64.
#define NN 50000
#define NE 800000
#define DD 64
#define NT (NN / 16)     // 3125 node-tiles of 16
#define NB 196           // scan blocks: 196*256 = 50176 >= NN
#define NPART 8          // dst partitions ~ XCDs
#define PSIZE (NN / NPART)        // 6250 nodes per partition
#define NCHUNK 128                // edge chunks per partition
#define ECHUNK (NE / NCHUNK)      // 6250 edges per chunk

typedef float     f32x4 __attribute__((ext_vector_type(4)));
typedef _Float16  f16x8 __attribute__((ext_vector_type(8)));
typedef _Float16  f16x4 __attribute__((ext_vector_type(4)));

// ---------------------------------------------------------------------------
// Fused: convert x [N,64] f32 -> fp16 + 4 weight mats -> fp16  ||  partitioned
// dst histogram (XCD-local atomics: block b -> partition (b&7) via round-robin
// blockIdx->XCD dispatch; each partition scans all dst, keeps its range).
// ---------------------------------------------------------------------------
__global__ void conv_hist_kernel(const float* __restrict__ x,
                                 const float* __restrict__ w0, const float* __restrict__ w1,
                                 const float* __restrict__ w2, const float* __restrict__ w3,
                                 _Float16* __restrict__ xh, _Float16* __restrict__ wh,
                                 const int* __restrict__ ei, int* __restrict__ counts) {
    const int CONV_BLOCKS = 3173;               // (800000 + 12288 quads) / 256
    if (blockIdx.x < CONV_BLOCKS) {
        int i = blockIdx.x * 256 + threadIdx.x; // quad index
        const int XQ = NN * DD / 4;             // 800000 quads of x
        if (i < XQ) {
            float4 v = ((const float4*)x)[i];
            f16x4 o = { (_Float16)v.x, (_Float16)v.y, (_Float16)v.z, (_Float16)v.w };
            ((f16x4*)xh)[i] = o;
        } else {
            int wi = i - XQ;                    // 4 mats * 3072 quads
            if (wi >= 4 * 3072) return;
            int mat = wi / 3072, q = wi - mat * 3072;
            const float* s = mat == 0 ? w0 : mat == 1 ? w1 : mat == 2 ? w2 : w3;
            float4 v = ((const float4*)s)[q];
            f16x4 o = { (_Float16)v.x, (_Float16)v.y, (_Float16)v.z, (_Float16)v.w };
            ((f16x4*)(wh + mat * 12288))[q] = o;
        }
    } else {
        int part = blockIdx.x & 7;              // ~XCD id (round-robin dispatch)
        int chunk = (blockIdx.x - CONV_BLOCKS) >> 3;
        int dlo = part * PSIZE, dhi = dlo + PSIZE;
        int base = chunk * ECHUNK;
        for (int i = threadIdx.x; i < ECHUNK; i += 256) {
            int dst = ei[NE + base + i];
            if (dst >= dlo && dst < dhi) atomicAdd(&counts[dst], 1);
        }
    }
}

// ---------------------------------------------------------------------------
// Parallel exclusive scan of counts[NN] -> off[NN+1], cursor[NN].
// ---------------------------------------------------------------------------
__global__ void scan1_kernel(const int* __restrict__ counts, int* __restrict__ bsum) {
    __shared__ int red[256];
    int i = blockIdx.x * 256 + threadIdx.x;
    int v = (i < NN) ? counts[i] : 0;
    red[threadIdx.x] = v;
    __syncthreads();
    for (int d = 128; d > 0; d >>= 1) {
        if (threadIdx.x < d) red[threadIdx.x] += red[threadIdx.x + d];
        __syncthreads();
    }
    if (threadIdx.x == 0) bsum[blockIdx.x] = red[0];
}

__global__ void scan2_kernel(const int* __restrict__ bsum, int* __restrict__ bofs,
                             int* __restrict__ off) {
    __shared__ int tmp[256];
    int t = threadIdx.x;
    int v = (t < NB) ? bsum[t] : 0;
    tmp[t] = v;
    __syncthreads();
    #pragma unroll
    for (int d = 1; d < 256; d <<= 1) {
        int add = (t >= d) ? tmp[t - d] : 0;
        __syncthreads();
        tmp[t] += add;
        __syncthreads();
    }
    if (t < NB) bofs[t] = tmp[t] - v;           // exclusive
    if (t == 255) off[NN] = tmp[255];           // total == NE
}

__global__ void scan3_kernel(const int* __restrict__ counts, const int* __restrict__ bofs,
                             int* __restrict__ off, int* __restrict__ cursor) {
    __shared__ int tmp[256];
    int t = threadIdx.x;
    int i = blockIdx.x * 256 + t;
    int v = (i < NN) ? counts[i] : 0;
    tmp[t] = v;
    __syncthreads();
    #pragma unroll
    for (int d = 1; d < 256; d <<= 1) {
        int add = (t >= d) ? tmp[t - d] : 0;
        __syncthreads();
        tmp[t] += add;
        __syncthreads();
    }
    if (i < NN) {
        int exc = bofs[blockIdx.x] + tmp[t] - v;
        off[i] = exc;
        cursor[i] = exc;
    }
}

// ---------------------------------------------------------------------------
// Partitioned reorder: block b -> dst partition (b&7), edge chunk (b>>3).
// Each partition's se region (~800KB) + cursor slice (~25KB) stay in its
// XCD's L2 -> scattered writes stop thrashing lines cross-XCD.
// ---------------------------------------------------------------------------
__global__ void reorder_kernel(const int* __restrict__ ei, const float* __restrict__ ew,
                               int* __restrict__ cursor, int2* __restrict__ se) {
    int part = blockIdx.x & 7;
    int chunk = blockIdx.x >> 3;
    int dlo = part * PSIZE, dhi = dlo + PSIZE;
    int base = chunk * ECHUNK;
    for (int i = threadIdx.x; i < ECHUNK; i += 256) {
        int e = base + i;
        int dst = ei[NE + e];
        if (dst >= dlo && dst < dhi) {
            int pos = atomicAdd(&cursor[dst], 1);
            se[pos] = make_int2(ei[e], __float_as_int(ew[e]));
        }
    }
}

// ---------------------------------------------------------------------------
// Aggregation: one wave per node, lane = d-channel. 8-deep edge pipeline:
// per round, 8 consecutive se entries (vectorizable) then 8 independent 128B
// row gathers in flight; ceil(n/8) full-width rounds with weight masking
// (no serial scalar tail; se has 64B slack so overreads stay in-bounds).
// ---------------------------------------------------------------------------
__global__ __launch_bounds__(256) void aggr_kernel(const int* __restrict__ off,
                                                   const int2* __restrict__ se,
                                                   const _Float16* __restrict__ xh,
                                                   _Float16* __restrict__ aggrh) {
    int wv = (blockIdx.x * 256 + threadIdx.x) >> 6;
    if (wv >= NN) return;
    int lane = threadIdx.x & 63;
    int s = off[wv], e = off[wv + 1];
    int n = e - s;
    const int2* sp = se + s;
    float acc = 0.f;
    for (int i = 0; i < n; i += 8) {
        int2 E[8];
        #pragma unroll
        for (int j = 0; j < 8; ++j) E[j] = sp[i + j];          // 4x dwordx4
        float a[8];
        #pragma unroll
        for (int j = 0; j < 8; ++j) a[j] = (float)xh[E[j].x * DD + lane];
        #pragma unroll
        for (int j = 0; j < 8; ++j) {
            float w = (i + j < n) ? __int_as_float(E[j].y) : 0.f;
            acc += a[j] * w;
        }
    }
    aggrh[wv * DD + lane] = (_Float16)acc;
}

// ---------------------------------------------------------------------------
// Fused GRU cell with fp16 MFMA. One wave per 16-node tile.
// A/B fragments use the SAME k mapping (8 contiguous per lane) -> result exact
// under any HW per-lane k permutation. C/D: col=lane&15, row=(lane>>4)*4+reg.
// ---------------------------------------------------------------------------
__global__ __launch_bounds__(256) void gru_kernel(
    const _Float16* __restrict__ aggrh,  // [N,64] fp16 (from aggregation)
    const _Float16* __restrict__ hA,     // [N,64] fp16: h (x or h1)
    const _Float16* __restrict__ wih,    // [192*64] fp16
    const _Float16* __restrict__ whh,    // [192*64] fp16
    const float* __restrict__ bih, const float* __restrict__ bhh,
    float* __restrict__ outF,            // layer2: d_out f32 (or null)
    _Float16* __restrict__ outH)         // layer1: h1 fp16 (or null)
{
    // Weights in LDS, rows padded 64->72 halves (144B: 16B-aligned, 2-way banks = free)
    __shared__ _Float16 W[2 * 192 * 72];
    #pragma unroll
    for (int it = 0; it < 12; ++it) {
        int idx = threadIdx.x + it * 256;          // 3072 vec8 = 2 mats * 192 rows * 8
        int mat = idx >= 1536 ? 1 : 0;
        int lid = idx - mat * 1536;
        int o = lid >> 3, k8 = (lid & 7) << 3;
        f16x8 v = *(const f16x8*)((mat ? whh : wih) + o * 64 + k8);
        *(f16x8*)&W[mat * 13824 + o * 72 + k8] = v;
    }
    __syncthreads();

    int lane = threadIdx.x & 63;
    int tile = blockIdx.x * 4 + (threadIdx.x >> 6);
    if (tile >= NT) return;
    int base = tile << 4;
    int c = lane & 15, g = lane >> 4;

    // A fragments: lane holds row (base+c), k = s*32 + g*8 .. +7
    f16x8 Aa[2], Ah[2];
    {
        const _Float16* ap = aggrh + (base + c) * DD + g * 8;
        const _Float16* hp = hA    + (base + c) * DD + g * 8;
        #pragma unroll
        for (int s = 0; s < 2; ++s) {
            Aa[s] = *(const f16x8*)(ap + s * 32);
            Ah[s] = *(const f16x8*)(hp + s * 32);
        }
    }

    f32x4 acc[12], hn[4];
    #pragma unroll
    for (int t = 0; t < 12; ++t) acc[t] = f32x4{0.f, 0.f, 0.f, 0.f};
    #pragma unroll
    for (int t = 0; t < 4; ++t) hn[t] = f32x4{0.f, 0.f, 0.f, 0.f};

    // gi for all 12 out-tiles (o = t*16+c)
    #pragma unroll
    for (int t = 0; t < 12; ++t) {
        #pragma unroll
        for (int s = 0; s < 2; ++s) {
            f16x8 b = *(const f16x8*)&W[(t * 16 + c) * 72 + s * 32 + g * 8];
            acc[t] = __builtin_amdgcn_mfma_f32_16x16x32_f16(Aa[s], b, acc[t], 0, 0, 0);
        }
    }
    // gh for r,z tiles (0..7): accumulate into the same acc (only sum needed)
    #pragma unroll
    for (int t = 0; t < 8; ++t) {
        #pragma unroll
        for (int s = 0; s < 2; ++s) {
            f16x8 b = *(const f16x8*)&W[13824 + (t * 16 + c) * 72 + s * 32 + g * 8];
            acc[t] = __builtin_amdgcn_mfma_f32_16x16x32_f16(Ah[s], b, acc[t], 0, 0, 0);
        }
    }
    // gh for n tiles (8..11): separate h_n
    #pragma unroll
    for (int t = 0; t < 4; ++t) {
        #pragma unroll
        for (int s = 0; s < 2; ++s) {
            f16x8 b = *(const f16x8*)&W[13824 + ((t + 8) * 16 + c) * 72 + s * 32 + g * 8];
            hn[t] = __builtin_amdgcn_mfma_f32_16x16x32_f16(Ah[s], b, hn[t], 0, 0, 0);
        }
    }

    // biases (lane-local, d = j*16 + c)
    float br[4], bz[4], bi_[4], bh_[4];
    #pragma unroll
    for (int j = 0; j < 4; ++j) {
        int d = j * 16 + c;
        br[j] = bih[d] + bhh[d];
        bz[j] = bih[64 + d] + bhh[64 + d];
        bi_[j] = bih[128 + d];
        bh_[j] = bhh[128 + d];
    }

    // gates + output. C layout: row (node) = g*4+m, col (d-slot) = c.
    #pragma unroll
    for (int m = 0; m < 4; ++m) {
        int n = base + g * 4 + m;
        #pragma unroll
        for (int j = 0; j < 4; ++j) {
            int d = j * 16 + c;
            float rv = 1.f / (1.f + __expf(-(acc[j][m] + br[j])));
            float zv = 1.f / (1.f + __expf(-(acc[4 + j][m] + bz[j])));
            float nv = tanhf(acc[8 + j][m] + bi_[j] + rv * (hn[j][m] + bh_[j]));
            float hold = (float)hA[n * DD + d];
            float o = (1.f - zv) * nv + zv * hold;
            if (outF) outF[n * DD + d] = o;
            else      outH[n * DD + d] = (_Float16)o;
        }
    }
}

// ---------------------------------------------------------------------------
extern "C" void kernel_launch(void* const* d_in, const int* in_sizes, int n_in,
                              void* d_out, int out_size, void* d_ws, size_t ws_size,
                              hipStream_t stream) {
    const float* x    = (const float*)d_in[0];
    const int*   ei   = (const int*)d_in[1];     // [2,E] int32
    const float* ew   = (const float*)d_in[2];   // [E,1]
    const float* wih1 = (const float*)d_in[3];
    const float* whh1 = (const float*)d_in[4];
    const float* bih1 = (const float*)d_in[5];
    const float* bhh1 = (const float*)d_in[6];
    const float* wih2 = (const float*)d_in[7];
    const float* whh2 = (const float*)d_in[8];
    const float* bih2 = (const float*)d_in[9];
    const float* bhh2 = (const float*)d_in[10];
    float* out = (float*)d_out;

    // workspace layout (bytes):
    //   xh 6.4MB | h1h 6.4MB | aggrh 6.4MB | se 6.4MB+64B slack | wh 96KB
    //   counts 200KB | off 200KB | cursor 200KB | bsum/bofs ~2KB
    char* ws = (char*)d_ws;
    _Float16* xh     = (_Float16*)ws;
    _Float16* h1h    = (_Float16*)(ws + 6400000);
    _Float16* aggrh  = (_Float16*)(ws + 12800000);
    int2*     se     = (int2*)    (ws + 19200000);
    _Float16* wh     = (_Float16*)(ws + 25600064);
    int*      counts = (int*)     (ws + 25700064);
    int*      off    = (int*)     (ws + 25900068);
    int*      cursor = (int*)     (ws + 26100072);
    int*      bsum   = (int*)     (ws + 26300076);
    int*      bofs   = (int*)     (ws + 26301076);

    (void)hipMemsetAsync(counts, 0, NN * sizeof(int), stream);
    (void)hipMemsetAsync(se + NE, 0, 64, stream);   // slack for 8-wide overread

    // convert (x + weights -> fp16) || partitioned histogram, one launch
    conv_hist_kernel<<<3173 + NPART * NCHUNK, 256, 0, stream>>>(
        x, wih1, whh1, wih2, whh2, xh, wh, ei, counts);
    // parallel scan -> off/cursor
    scan1_kernel<<<NB, 256, 0, stream>>>(counts, bsum);
    scan2_kernel<<<1, 256, 0, stream>>>(bsum, bofs, off);
    scan3_kernel<<<NB, 256, 0, stream>>>(counts, bofs, off, cursor);
    // partitioned reorder (XCD-local scatter)
    reorder_kernel<<<NPART * NCHUNK, 256, 0, stream>>>(ei, ew, cursor, se);

    // ---- layer 1 ----
    aggr_kernel<<<NN * 64 / 256, 256, 0, stream>>>(off, se, xh, aggrh);
    gru_kernel<<<(NT + 3) / 4, 256, 0, stream>>>(aggrh, xh,
                                                 wh, wh + 12288, bih1, bhh1,
                                                 nullptr, h1h);

    // ---- layer 2 ----
    aggr_kernel<<<NN * 64 / 256, 256, 0, stream>>>(off, se, h1h, aggrh);
    gru_kernel<<<(NT + 3) / 4, 256, 0, stream>>>(aggrh, h1h,
                                                 wh + 2 * 12288, wh + 3 * 12288, bih2, bhh2,
                                                 out, nullptr);
}